// Round 3
// baseline (169.082 us; speedup 1.0000x reference)
//
#include <hip/hip_runtime.h>

#define HH 512
#define WW 512
#define NIMG 32

typedef float v4f __attribute__((ext_vector_type(4)));

// One wave (64 lanes) == one full image row (64 * 8 px = 512).
// => h-edge branches are wave-uniform; only lanes 0/63 diverge on w-halos.
__global__ __launch_bounds__(256) void edge_mag_kernel(const float* __restrict__ x,
                                                       float* __restrict__ out) {
    int tid    = blockIdx.x * blockDim.x + threadIdx.x;
    int lane   = tid & 63;        // position within the row
    int row_id = tid >> 6;        // global row index (n*512 + h)
    int h      = row_id & (HH - 1);
    int n      = row_id >> 9;     // row_id / 512
    int w8     = lane << 3;       // first of 8 pixels handled by this thread

    const size_t plane = (size_t)HH * WW;
    const float* g    = x + ((size_t)n * 3 + 1) * plane;   // channel 1 only
    const float* rowc = g + (size_t)h * WW;

    // index 0 = left halo, 1..8 = pixels, 9 = right halo
    float c[10], t[10], b[10];

    {
        v4f v0 = *(const v4f*)(rowc + w8);
        v4f v1 = *(const v4f*)(rowc + w8 + 4);
        c[1] = v0.x; c[2] = v0.y; c[3] = v0.z; c[4] = v0.w;
        c[5] = v1.x; c[6] = v1.y; c[7] = v1.z; c[8] = v1.w;
        c[0] = (w8 > 0)       ? rowc[w8 - 1] : 0.f;   // only lane 0 diverges
        c[9] = (w8 + 8 < WW)  ? rowc[w8 + 8] : 0.f;   // only lane 63 diverges
    }

    if (h > 0) {   // wave-uniform branch
        const float* rowt = rowc - WW;
        v4f v0 = *(const v4f*)(rowt + w8);
        v4f v1 = *(const v4f*)(rowt + w8 + 4);
        t[1] = v0.x; t[2] = v0.y; t[3] = v0.z; t[4] = v0.w;
        t[5] = v1.x; t[6] = v1.y; t[7] = v1.z; t[8] = v1.w;
        t[0] = (w8 > 0)      ? rowt[w8 - 1] : 0.f;
        t[9] = (w8 + 8 < WW) ? rowt[w8 + 8] : 0.f;
    } else {
        #pragma unroll
        for (int i = 0; i < 10; i++) t[i] = 0.f;
    }

    if (h < HH - 1) {   // wave-uniform branch
        const float* rowb = rowc + WW;
        v4f v0 = *(const v4f*)(rowb + w8);
        v4f v1 = *(const v4f*)(rowb + w8 + 4);
        b[1] = v0.x; b[2] = v0.y; b[3] = v0.z; b[4] = v0.w;
        b[5] = v1.x; b[6] = v1.y; b[7] = v1.z; b[8] = v1.w;
        b[0] = (w8 > 0)      ? rowb[w8 - 1] : 0.f;
        b[9] = (w8 + 8 < WW) ? rowb[w8 + 8] : 0.f;
    } else {
        #pragma unroll
        for (int i = 0; i < 10; i++) b[i] = 0.f;
    }

    float res[8];
    #pragma unroll
    for (int j = 0; j < 8; j++) {
        float ctr = c[j + 1];
        float d0 = ctr - c[j + 2];
        float d1 = ctr - c[j];
        float d2 = ctr - b[j + 1];
        float d3 = ctr - t[j + 1];
        float d4 = ctr - b[j + 2];
        float d5 = ctr - b[j];
        float d6 = ctr - t[j + 2];
        float d7 = ctr - t[j];
        float s = d0*d0 + d1*d1 + d2*d2 + d3*d3
                + d4*d4 + d5*d5 + d6*d6 + d7*d7;
        res[j] = __builtin_amdgcn_sqrtf(s);   // raw v_sqrt_f32, ~1 ulp
    }
    v4f m0 = { res[0], res[1], res[2], res[3] };
    v4f m1 = { res[4], res[5], res[6], res[7] };

    float* o = out + (size_t)n * 3 * plane + (size_t)h * WW + w8;
    // non-temporal: don't let the 100 MB write stream evict reused input rows
    __builtin_nontemporal_store(m0, (v4f*)(o));
    __builtin_nontemporal_store(m1, (v4f*)(o + 4));
    __builtin_nontemporal_store(m0, (v4f*)(o + plane));
    __builtin_nontemporal_store(m1, (v4f*)(o + plane + 4));
    __builtin_nontemporal_store(m0, (v4f*)(o + 2 * plane));
    __builtin_nontemporal_store(m1, (v4f*)(o + 2 * plane + 4));
}

extern "C" void kernel_launch(void* const* d_in, const int* in_sizes, int n_in,
                              void* d_out, int out_size, void* d_ws, size_t ws_size,
                              hipStream_t stream) {
    const float* x = (const float*)d_in[0];
    float* out = (float*)d_out;
    const int total_threads = NIMG * HH * (WW / 8);   // 1,048,576
    const int block = 256;
    const int grid = total_threads / block;            // 4096
    edge_mag_kernel<<<grid, block, 0, stream>>>(x, out);
}